// Round 7
// baseline (291.815 us; speedup 1.0000x reference)
//
#include <hip/hip_runtime.h>
#include <hip/hip_bf16.h>

typedef __attribute__((ext_vector_type(8))) short bf16x8;
typedef __attribute__((ext_vector_type(16))) float f32x16;
typedef unsigned short ushort_t;

constexpr int NS  = 2048;  // n_symm
constexpr int F   = 64;    // out features
constexpr int IFT = 64;    // in features
constexpr int B   = 64;    // batch
constexpr int NCS = 144;   // half-spectrum cells: cs = ky*9 + kx, kx in 0..8, ky in 0..15

// cos/sin(2*pi*j/16)
constexpr float CT[16] = {
    1.0f,  0.9238795325112867f,  0.7071067811865476f,  0.3826834323650898f,
    0.0f, -0.3826834323650898f, -0.7071067811865476f, -0.9238795325112867f,
   -1.0f, -0.9238795325112867f, -0.7071067811865476f, -0.3826834323650898f,
    0.0f,  0.3826834323650898f,  0.7071067811865476f,  0.9238795325112867f};
constexpr float ST[16] = {
    0.0f,  0.3826834323650898f,  0.7071067811865476f,  0.9238795325112867f,
    1.0f,  0.9238795325112867f,  0.7071067811865476f,  0.3826834323650898f,
    0.0f, -0.3826834323650898f, -0.7071067811865476f, -0.9238795325112867f,
   -1.0f, -0.9238795325112867f, -0.7071067811865476f, -0.3826834323650898f};

// digit-reverse base 4: X[k] lives in slot DR4[k] after fft16
constexpr int DR4[16] = {0,4,8,12, 1,5,9,13, 2,6,10,14, 3,7,11,15};

template<bool INV>
__device__ inline void dft4(float& ar, float& ai, float& br, float& bi,
                            float& cr, float& ci, float& dr, float& di)
{
    const float t0r = ar + cr, t0i = ai + ci;
    const float t1r = ar - cr, t1i = ai - ci;
    const float t2r = br + dr, t2i = bi + di;
    const float t3r = br - dr, t3i = bi - di;
    ar = t0r + t2r; ai = t0i + t2i;
    cr = t0r - t2r; ci = t0i - t2i;
    if (!INV) { br = t1r + t3i; bi = t1i - t3r; dr = t1r - t3i; di = t1i + t3r; }
    else      { br = t1r - t3i; bi = t1i + t3r; dr = t1r + t3i; di = t1i - t3r; }
}

// radix-4 DIT FFT-16, in place, natural input, digit-reversed output (slot DR4[k]).
template<bool INV>
__device__ inline void fft16(float* xr, float* xi)
{
#pragma unroll
    for (int r = 0; r < 4; ++r)
        dft4<INV>(xr[r], xi[r], xr[r + 4], xi[r + 4],
                  xr[r + 8], xi[r + 8], xr[r + 12], xi[r + 12]);
#pragma unroll
    for (int r = 1; r < 4; ++r)
#pragma unroll
        for (int q = 1; q < 4; ++q) {
            const int t = (r * q) & 15;
            const int s = r + 4 * q;
            if (t == 4) {
                const float tr = xr[s];
                if (!INV) { xr[s] = xi[s];  xi[s] = -tr; }
                else      { xr[s] = -xi[s]; xi[s] = tr;  }
            } else {
                const float c = CT[t], sn = INV ? ST[t] : -ST[t];
                const float tr = xr[s];
                xr[s] = tr * c - xi[s] * sn;
                xi[s] = tr * sn + xi[s] * c;
            }
        }
#pragma unroll
    for (int q = 0; q < 4; ++q)
        dft4<INV>(xr[4 * q], xi[4 * q], xr[4 * q + 1], xi[4 * q + 1],
                  xr[4 * q + 2], xi[4 * q + 2], xr[4 * q + 3], xi[4 * q + 3]);
}

__device__ inline float bf2f(ushort_t h) { return __uint_as_float(((unsigned)h) << 16); }

// packed RNE f32x2 -> bf16x2 (low = a, high = b)
__device__ inline unsigned pkbf(float a, float b) {
    union { __hip_bfloat162 h2; unsigned u; } c;
    c.h2 = __float22bfloat162_rn(make_float2(a, b));
    return c.u;
}

__device__ inline bf16x8 bneg(bf16x8 v) {
    union { bf16x8 b; unsigned u[4]; } x; x.b = v;
    x.u[0] ^= 0x80008000u; x.u[1] ^= 0x80008000u;
    x.u[2] ^= 0x80008000u; x.u[3] ^= 0x80008000u;
    return x.b;
}

// ---------------------------------------------------------------------------
// pt2[a][bq][s] = pt[a][s*8+bq]
// ---------------------------------------------------------------------------
__global__ __launch_bounds__(256) void permute_pt_kernel(
    const int* __restrict__ pt, int* __restrict__ pt2)
{
    const int t = blockIdx.x * 256 + threadIdx.x;   // 16384
    const int a = t >> 11, r = t & 2047;
    const int bq = r >> 8, s = r & 255;
    pt2[t] = pt[a * NS + s * 8 + bq];
}

// ---------------------------------------------------------------------------
// fft_x: x[b,i,s*8+a] -> A-fragments, plane-major:
// xf[(kb*8 + mt*4 + v)*NCS*512 + cs*512 + lane*8 + j], v in {rh,rl,ih,il}
// stgx word layout per (cs,bloc,a): w0 = (rh|ih<<16), w1 = (rl|il<<16)
// ---------------------------------------------------------------------------
__global__ __launch_bounds__(256, 4) void fft_x_kernel(
    const float* __restrict__ x, ushort_t* __restrict__ xf, int i0, int KB)
{
    __shared__ float t_re[16][152], t_im[16][152];
    __shared__ ushort_t stgx[NCS * 68];
    const int tid = threadIdx.x;
    const int bp = blockIdx.x;   // 0..31
    const int il = blockIdx.y;   // 0..CI-1

    const int g = tid >> 4, l = tid & 15;
    const int bloc = g & 1, a = g >> 1;
    const int b = bp * 2 + bloc;
    const int i = i0 + il;

    // pass 1: row sy=l, real-input FFT-16 over sx, keep kx 0..8
    const float* xr_g = x + ((size_t)b * IFT + i) * NS;
    float xr[16], xi[16];
#pragma unroll
    for (int sx = 0; sx < 16; ++sx) { xr[sx] = xr_g[(l * 16 + sx) * 8 + a]; xi[sx] = 0.f; }
    fft16<false>(xr, xi);
#pragma unroll
    for (int kx = 0; kx < 9; ++kx) {
        t_re[g][kx * 17 + l] = xr[DR4[kx]];
        t_im[g][kx * 17 + l] = xi[DR4[kx]];
    }
    __syncthreads();

    // pass 2: column kx=l (l<9), complex FFT-16 over sy
    if (l < 9) {
        float Tr[16], Ti[16];
#pragma unroll
        for (int n = 0; n < 16; ++n) { Tr[n] = t_re[g][l * 17 + n]; Ti[n] = t_im[g][l * 17 + n]; }
        fft16<false>(Tr, Ti);
#pragma unroll
        for (int ky = 0; ky < 16; ++ky) {
            const float sr = Tr[DR4[ky]], si = Ti[DR4[ky]];
            const int cs = ky * 9 + l;
            const unsigned w0 = pkbf(sr, si);                       // rh | ih<<16
            const float rhf = bf2f((ushort_t)(w0 & 0xffffu));
            const float ihf = bf2f((ushort_t)(w0 >> 16));
            const unsigned w1 = pkbf(sr - rhf, si - ihf);           // rl | il<<16
            *(uint2*)&stgx[cs * 68 + bloc * 32 + a * 4] = make_uint2(w0, w1);
        }
    }
    __syncthreads();

    // fragment assembly, plane-major write
    const int kb = il >> 1, mt = bp >> 4;
    const int lb = (il & 1) * 32 + (bp & 15) * 2;
    const size_t PS = (size_t)NCS * 512;
    for (int t = tid; t < NCS * 8; t += 256) {
        const int cs = t >> 3, v4 = (t >> 1) & 3, h = t & 1;
        // ushort slot within 4-group: v {rh,rl,ih,il} -> {0,2,1,3}
        const int us = ((v4 & 1) << 1) | (v4 >> 1);
        union { ushort_t s[8]; uint4 u; } tmp;
        const int base = cs * 68 + h * 32 + us;
#pragma unroll
        for (int j = 0; j < 8; ++j) tmp.s[j] = stgx[base + j * 4];
        const size_t off = (size_t)(kb * 8 + mt * 4 + v4) * PS + (size_t)cs * 512 + (size_t)(lb + h) * 8;
        *(uint4*)(xf + off) = tmp.u;
    }
}

// ---------------------------------------------------------------------------
// fft_k: gather kernel[f,i,pt[a][s*8+bq]] -> B-fragments, plane-major:
// kf[(kb*32 + nt*2 + v)*NCS*512 + cs*512 + lane*8 + j], v in {re, im}
// LDS: krow2 (16 KB) aliases the low half of t2 (live ranges disjoint);
// total 30 KB -> 5 blocks/CU. Packed pass-2 (144 threads), packed bf16 cvt.
// ---------------------------------------------------------------------------
__global__ __launch_bounds__(256, 4) void fft_k_kernel(
    const float* __restrict__ kern, const int* __restrict__ pt2,
    ushort_t* __restrict__ kf, int i0, int KB)
{
    __shared__ __align__(16) float2 t2[16 * 153];      // 19584 B; first 2048 double as krow2
    __shared__ __align__(16) unsigned stgk[NCS * 18];  // 10368 B
    float2* krow2 = &t2[0];

    const int tid = threadIdx.x;
    const int fg  = blockIdx.x & 15;   // slow-varying f-group for XCD locality
    const int bqp = blockIdx.x >> 4;
    const int il  = blockIdx.y;
    const int i   = i0 + il;

    const int g = tid >> 4, l = tid & 15;
    const int bql = g & 1, a = g >> 1;
    const int bq  = bqp * 2 + bql;

    // gather indices (constant across rounds)
    int idx[16];
    const int4* pp = (const int4*)(pt2 + ((a * 8 + bq) * 256 + l * 16));
#pragma unroll
    for (int q = 0; q < 4; ++q) {
        const int4 t4 = pp[q];
        idx[q * 4] = t4.x; idx[q * 4 + 1] = t4.y; idx[q * 4 + 2] = t4.z; idx[q * 4 + 3] = t4.w;
    }

    const int kb = il >> 1;
    const int nt = fg;
    // packed pass-2 mapping: column job tid<144 -> transform pg, column pl
    const int pg = (tid * 57) >> 9;       // tid/9 for tid<144
    const int pl = tid - pg * 9;
    const int slot = (pg & 1) * 8 + (pg >> 1);
    const size_t PS = (size_t)NCS * 512;

    for (int fr2 = 0; fr2 < 2; ++fr2) {
        const int f0 = fg * 4 + fr2 * 2;
        // trailing sync of previous sub-loop guarantees t2 reads are done
        {
            const float4* s0 = (const float4*)(kern + ((size_t)f0 * IFT + i) * NS);
            const float4* s1 = (const float4*)(kern + ((size_t)(f0 + 1) * IFT + i) * NS);
            for (int u = tid; u < 512; u += 256) {
                const float4 va = s0[u], vb = s1[u];
                float4* dst = (float4*)(krow2 + (size_t)u * 4);
                dst[0] = make_float4(va.x, vb.x, va.y, vb.y);
                dst[1] = make_float4(va.z, vb.z, va.w, vb.w);
            }
        }
        __syncthreads();
        float2 v2[16];
#pragma unroll
        for (int sx = 0; sx < 16; ++sx) v2[sx] = krow2[idx[sx]];
        __syncthreads();   // krow2 dead; its region is reused as t2 below

        for (int sub = 0; sub < 2; ++sub) {
            // pass 1 from registers: real FFT-16 over sx, rows sy=l, keep kx 0..8
            {
                float xr[16], xi[16];
#pragma unroll
                for (int sx = 0; sx < 16; ++sx) { xr[sx] = sub ? v2[sx].y : v2[sx].x; xi[sx] = 0.f; }
                fft16<false>(xr, xi);
#pragma unroll
                for (int kx = 0; kx < 9; ++kx)
                    t2[g * 153 + kx * 17 + l] = make_float2(xr[DR4[kx]], xi[DR4[kx]]);
            }
            __syncthreads();

            // pass 2 packed: complex FFT-16 over sy, 144 active threads
            if (tid < 144) {
                float Tr[16], Ti[16];
#pragma unroll
                for (int n = 0; n < 16; ++n) {
                    const float2 tv = t2[pg * 153 + pl * 17 + n];
                    Tr[n] = tv.x; Ti[n] = tv.y;
                }
                fft16<false>(Tr, Ti);
#pragma unroll
                for (int ky = 0; ky < 16; ++ky) {
                    const int cs = ky * 9 + pl;
                    stgk[cs * 18 + slot] = pkbf(Tr[DR4[ky]], Ti[DR4[ky]]);
                }
            }
            __syncthreads();

            // fragment assembly, plane-major write
            const int f = f0 + sub;
            const int lbase = (il & 1) * 32 + (f & 3) * 8 + bqp * 2;
            for (int t = tid; t < NCS * 2; t += 256) {
                const int cs = t >> 1, h = t & 1;
                const int base = cs * 18 + h * 8;
                unsigned w[8];
                *(uint2*)&w[0] = *(const uint2*)&stgk[base];
                *(uint2*)&w[2] = *(const uint2*)&stgk[base + 2];
                *(uint2*)&w[4] = *(const uint2*)&stgk[base + 4];
                *(uint2*)&w[6] = *(const uint2*)&stgk[base + 6];
                union { ushort_t s[8]; uint4 u; } lo, hi;
#pragma unroll
                for (int j = 0; j < 8; ++j) { lo.s[j] = (ushort_t)(w[j] & 0xffffu); hi.s[j] = (ushort_t)(w[j] >> 16); }
                const size_t off = (size_t)(kb * 32 + nt * 2) * PS + (size_t)cs * 512 + (size_t)(lbase + h) * 8;
                *(uint4*)(kf + off) = lo.u;
                *(uint4*)(kf + off + PS) = hi.u;
            }
            __syncthreads();
        }
    }
}

// ---------------------------------------------------------------------------
// MFMA complex GEMM, A split-bf16 (hi/lo), B plain bf16, no LDS.
// Plane-major operands; grid (NCS, 4) so same-cs blocks share an XCD (A in L2).
// ---------------------------------------------------------------------------
#define MFMA(acc, A, Bv) acc = __builtin_amdgcn_mfma_f32_32x32x16_bf16(A, Bv, acc, 0, 0, 0)
#define LDB(p) (*(const bf16x8*)(p))

__global__ __launch_bounds__(256) void gemm_kernel(
    const ushort_t* __restrict__ xf, const ushort_t* __restrict__ kf,
    float* __restrict__ yre, float* __restrict__ yim, int KB, int acc)
{
    const int cs = blockIdx.x, nb = blockIdx.y;
    const int w = threadIdx.x >> 6, lane = threadIdx.x & 63;
    const int nt = nb * 4 + w;
    const size_t PS = (size_t)NCS * 512;

    f32x16 cre0, cim0, cre1, cim1;
#pragma unroll
    for (int q = 0; q < 16; ++q) { cre0[q] = 0.f; cim0[q] = 0.f; cre1[q] = 0.f; cim1[q] = 0.f; }

    const ushort_t* ab = xf + (size_t)cs * 512 + (size_t)lane * 8;
    const ushort_t* bb = kf + (size_t)cs * 512 + (size_t)(nt * 2) * PS + (size_t)lane * 8;

    const ushort_t* ap = ab;                 // planes kb*8 + {0..7}
    const ushort_t* bp = bb;                 // planes kb*32 + nt*2 + {0,1}
    bf16x8 Brh = LDB(bp), Bih = LDB(bp + PS);
    bf16x8 Arh0 = LDB(ap), Arl0 = LDB(ap + PS), Aih0 = LDB(ap + 2 * PS), Ail0 = LDB(ap + 3 * PS);
    bf16x8 Arh1 = LDB(ap + 4 * PS), Arl1 = LDB(ap + 5 * PS), Aih1 = LDB(ap + 6 * PS), Ail1 = LDB(ap + 7 * PS);

    for (int kb = 0; kb < KB; ++kb) {
        const int kn = (kb + 1 < KB) ? kb + 1 : kb;
        const ushort_t* an = ab + (size_t)kn * 8 * PS;
        const ushort_t* bn = bb + (size_t)kn * 32 * PS;
        const bf16x8 nBrh = LDB(bn), nBih = LDB(bn + PS);
        const bf16x8 nArh0 = LDB(an), nArl0 = LDB(an + PS), nAih0 = LDB(an + 2 * PS), nAil0 = LDB(an + 3 * PS);
        const bf16x8 nArh1 = LDB(an + 4 * PS), nArl1 = LDB(an + 5 * PS), nAih1 = LDB(an + 6 * PS), nAil1 = LDB(an + 7 * PS);

        const bf16x8 NAih0 = bneg(Aih0), NAil0 = bneg(Ail0);
        const bf16x8 NAih1 = bneg(Aih1), NAil1 = bneg(Ail1);

        MFMA(cre0, Arh0, Brh); MFMA(cre0, Arl0, Brh);
        MFMA(cre0, NAih0, Bih); MFMA(cre0, NAil0, Bih);
        MFMA(cim0, Arh0, Bih); MFMA(cim0, Arl0, Bih);
        MFMA(cim0, Aih0, Brh); MFMA(cim0, Ail0, Brh);
        MFMA(cre1, Arh1, Brh); MFMA(cre1, Arl1, Brh);
        MFMA(cre1, NAih1, Bih); MFMA(cre1, NAil1, Bih);
        MFMA(cim1, Arh1, Bih); MFMA(cim1, Arl1, Bih);
        MFMA(cim1, Aih1, Brh); MFMA(cim1, Ail1, Brh);

        Brh = nBrh; Bih = nBih;
        Arh0 = nArh0; Arl0 = nArl0; Aih0 = nAih0; Ail0 = nAil0;
        Arh1 = nArh1; Arl1 = nArl1; Aih1 = nAih1; Ail1 = nAil1;
    }

    // C/D layout: col=lane&31, row=(reg&3)+8*(reg>>2)+4*(lane>>5)
    const int col = lane & 31, rhi = (lane >> 5) * 4;
    const int n = nb * 128 + w * 32 + col;
#pragma unroll
    for (int mt = 0; mt < 2; ++mt) {
        const f32x16 cr = mt ? cre1 : cre0;
        const f32x16 ci = mt ? cim1 : cim0;
#pragma unroll
        for (int reg = 0; reg < 16; ++reg) {
            const int row = (reg & 3) + 8 * (reg >> 2) + rhi;
            const size_t off = ((size_t)cs * B + mt * 32 + row) * 512 + n;
            float vr = cr[reg], vi = ci[reg];
            if (acc) { vr += yre[off]; vi += yim[off]; }
            yre[off] = vr; yim[off] = vi;
        }
    }
}

// ---------------------------------------------------------------------------
// ifft: mirror half-spectrum (cs = ky*9+kx), 2D inverse FFT, +bias.
// ---------------------------------------------------------------------------
__global__ __launch_bounds__(256, 4) void ifft_y_kernel(
    const float* __restrict__ yre, const float* __restrict__ yim,
    const float* __restrict__ bias, float* __restrict__ out)
{
    __shared__ float yr_s[NCS][17], yi_s[NCS][17];
    __shared__ float t_re[16][271], t_im[16][271];
    __shared__ float ost[2][256][9];
    const int tid = threadIdx.x;
    const int ng = blockIdx.x;   // 0..31
    const int b = blockIdx.y;
    const int n0 = ng * 16;
    for (int t = tid; t < NCS * 16; t += 256) {
        const int cs = t >> 4, nl = t & 15;
        const size_t off = ((size_t)cs * B + b) * 512 + n0 + nl;
        yr_s[cs][nl] = yre[off];
        yi_s[cs][nl] = yim[off];
    }
    __syncthreads();

    const int g = tid >> 4, l = tid & 15;

    // pass 1: row ky=l, Hermitian mirror, inverse FFT-16 over kx
    float Yr[16], Yi[16];
#pragma unroll
    for (int kx = 0; kx < 16; ++kx) {
        if (kx <= 8) {
            const int cs = l * 9 + kx;
            Yr[kx] = yr_s[cs][g]; Yi[kx] = yi_s[cs][g];
        } else {
            const int cs = ((16 - l) & 15) * 9 + (16 - kx);
            Yr[kx] = yr_s[cs][g]; Yi[kx] = -yi_s[cs][g];
        }
    }
    fft16<true>(Yr, Yi);
#pragma unroll
    for (int sx = 0; sx < 16; ++sx) {
        t_re[g][sx * 17 + l] = Yr[DR4[sx]];
        t_im[g][sx * 17 + l] = Yi[DR4[sx]];
    }
    __syncthreads();

    // pass 2: column sx=l, inverse FFT-16 over ky, real part only
    float Tr[16], Ti[16];
#pragma unroll
    for (int n = 0; n < 16; ++n) { Tr[n] = t_re[g][l * 17 + n]; Ti[n] = t_im[g][l * 17 + n]; }
    fft16<true>(Tr, Ti);
    const int fl = g >> 3, pq = g & 7;
#pragma unroll
    for (int sy = 0; sy < 16; ++sy)
        ost[fl][sy * 16 + l][pq] = Tr[DR4[sy]] * (1.f / 256.f);
    __syncthreads();

    const int f0 = ng * 2;
    for (int t = tid; t < 4096; t += 256) {
        const int flv = t >> 11, e = t & 2047;
        out[((size_t)b * F + f0 + flv) * NS + e] = ost[flv][e >> 3][e & 7] + bias[f0 + flv];
    }
}

// ---------------------------------------------------------------------------
extern "C" void kernel_launch(void* const* d_in, const int* in_sizes, int n_in,
                              void* d_out, int out_size, void* d_ws, size_t ws_size,
                              hipStream_t stream)
{
    const float* x = (const float*)d_in[0];
    const float* kern = (const float*)d_in[1];
    const float* bias = (const float*)d_in[2];
    const int* pt = (const int*)d_in[3];
    float* out = (float*)d_out;

    // largest in-feature chunk CI that fits workspace
    int CI = 2;
    const int cands[6] = {64, 32, 16, 8, 4, 2};
    for (int t = 0; t < 6; ++t) {
        const int KBc = cands[t] / 2;
        const size_t need = 65536                          // pt2
                          + (size_t)NCS * KBc * 8192       // xf (4 planes bf16)
                          + (size_t)NCS * KBc * 32768      // kf (2 planes bf16)
                          + 2 * (size_t)NCS * B * 512 * 4; // yf re/im fp32
        if (need <= ws_size) { CI = cands[t]; break; }
    }
    const int KB = CI / 2;

    char* p = (char*)d_ws;
    int* pt2 = (int*)p;          p += 65536;
    ushort_t* xf = (ushort_t*)p; p += (size_t)NCS * KB * 8192;
    ushort_t* kf = (ushort_t*)p; p += (size_t)NCS * KB * 32768;
    float* yre = (float*)p;      p += (size_t)NCS * B * 512 * 4;
    float* yim = (float*)p;

    permute_pt_kernel<<<64, 256, 0, stream>>>(pt, pt2);

    const int nch = IFT / CI;
    for (int ch = 0; ch < nch; ++ch) {
        const int i0 = ch * CI;
        fft_x_kernel<<<dim3(32, CI), 256, 0, stream>>>(x, xf, i0, KB);
        fft_k_kernel<<<dim3(64, CI), 256, 0, stream>>>(kern, pt2, kf, i0, KB);
        gemm_kernel<<<dim3(NCS, 4), 256, 0, stream>>>(xf, kf, yre, yim, KB, ch > 0);
    }
    ifft_y_kernel<<<dim3(32, B), 256, 0, stream>>>(yre, yim, bias, out);
}

// Round 9
// 288.596 us; speedup vs baseline: 1.0112x; 1.0112x over previous
//
#include <hip/hip_runtime.h>
#include <hip/hip_bf16.h>

typedef __attribute__((ext_vector_type(8))) short bf16x8;
typedef __attribute__((ext_vector_type(16))) float f32x16;
typedef __attribute__((ext_vector_type(2))) float f32x2;
typedef unsigned short ushort_t;

constexpr int NS  = 2048;  // n_symm
constexpr int F   = 64;    // out features
constexpr int IFT = 64;    // in features
constexpr int B   = 64;    // batch
constexpr int NCS = 144;   // half-spectrum cells: cs = ky*9 + kx, kx in 0..8, ky in 0..15

// cos/sin(2*pi*j/16)
constexpr float CT[16] = {
    1.0f,  0.9238795325112867f,  0.7071067811865476f,  0.3826834323650898f,
    0.0f, -0.3826834323650898f, -0.7071067811865476f, -0.9238795325112867f,
   -1.0f, -0.9238795325112867f, -0.7071067811865476f, -0.3826834323650898f,
    0.0f,  0.3826834323650898f,  0.7071067811865476f,  0.9238795325112867f};
constexpr float ST[16] = {
    0.0f,  0.3826834323650898f,  0.7071067811865476f,  0.9238795325112867f,
    1.0f,  0.9238795325112867f,  0.7071067811865476f,  0.3826834323650898f,
    0.0f, -0.3826834323650898f, -0.7071067811865476f, -0.9238795325112867f,
   -1.0f, -0.9238795325112867f, -0.7071067811865476f, -0.3826834323650898f};

// digit-reverse base 4: X[k] lives in slot DR4[k] after fft16
constexpr int DR4[16] = {0,4,8,12, 1,5,9,13, 2,6,10,14, 3,7,11,15};

// ------------------------- scalar radix-4 FFT-16 (fft_x / ifft) ------------
template<bool INV>
__device__ inline void dft4(float& ar, float& ai, float& br, float& bi,
                            float& cr, float& ci, float& dr, float& di)
{
    const float t0r = ar + cr, t0i = ai + ci;
    const float t1r = ar - cr, t1i = ai - ci;
    const float t2r = br + dr, t2i = bi + di;
    const float t3r = br - dr, t3i = bi - di;
    ar = t0r + t2r; ai = t0i + t2i;
    cr = t0r - t2r; ci = t0i - t2i;
    if (!INV) { br = t1r + t3i; bi = t1i - t3r; dr = t1r - t3i; di = t1i + t3r; }
    else      { br = t1r - t3i; bi = t1i + t3r; dr = t1r + t3i; di = t1i - t3r; }
}

template<bool INV>
__device__ inline void fft16(float* xr, float* xi)
{
#pragma unroll
    for (int r = 0; r < 4; ++r)
        dft4<INV>(xr[r], xi[r], xr[r + 4], xi[r + 4],
                  xr[r + 8], xi[r + 8], xr[r + 12], xi[r + 12]);
#pragma unroll
    for (int r = 1; r < 4; ++r)
#pragma unroll
        for (int q = 1; q < 4; ++q) {
            const int t = (r * q) & 15;
            const int s = r + 4 * q;
            if (t == 4) {
                const float tr = xr[s];
                if (!INV) { xr[s] = xi[s];  xi[s] = -tr; }
                else      { xr[s] = -xi[s]; xi[s] = tr;  }
            } else {
                const float c = CT[t], sn = INV ? ST[t] : -ST[t];
                const float tr = xr[s];
                xr[s] = tr * c - xi[s] * sn;
                xi[s] = tr * sn + xi[s] * c;
            }
        }
#pragma unroll
    for (int q = 0; q < 4; ++q)
        dft4<INV>(xr[4 * q], xi[4 * q], xr[4 * q + 1], xi[4 * q + 1],
                  xr[4 * q + 2], xi[4 * q + 2], xr[4 * q + 3], xi[4 * q + 3]);
}

// --------------------- packed (v_pk_*_f32) complex FFT-16 ------------------
template<bool INV>
__device__ inline void dft4c(f32x2& a, f32x2& b, f32x2& c, f32x2& d)
{
    const f32x2 t0 = a + c, t1 = a - c;
    const f32x2 t2 = b + d, t3 = b - d;
    a = t0 + t2; c = t0 - t2;
    f32x2 jt3;
    if (!INV) { jt3.x = t3.y;  jt3.y = -t3.x; }   // -i*t3
    else      { jt3.x = -t3.y; jt3.y = t3.x;  }   // +i*t3
    b = t1 + jt3; d = t1 - jt3;
}

template<bool INV>
__device__ inline void fft16c(f32x2* z)
{
#pragma unroll
    for (int r = 0; r < 4; ++r) dft4c<INV>(z[r], z[r + 4], z[r + 8], z[r + 12]);
#pragma unroll
    for (int r = 1; r < 4; ++r)
#pragma unroll
        for (int q = 1; q < 4; ++q) {
            const int t = (r * q) & 15, s = r + 4 * q;
            if (t == 4) {
                const f32x2 v = z[s];
                if (!INV) { z[s].x = v.y;  z[s].y = -v.x; }
                else      { z[s].x = -v.y; z[s].y = v.x;  }
            } else {
                const float c = CT[t], sn = INV ? ST[t] : -ST[t];
                const f32x2 v = z[s];
                f32x2 w;
                w.x = v.x * c - v.y * sn;
                w.y = v.x * sn + v.y * c;
                z[s] = w;
            }
        }
#pragma unroll
    for (int q = 0; q < 4; ++q) dft4c<INV>(z[4 * q], z[4 * q + 1], z[4 * q + 2], z[4 * q + 3]);
}

__device__ inline float bf2f(ushort_t h) { return __uint_as_float(((unsigned)h) << 16); }

// packed RNE f32x2 -> bf16x2 (low = a, high = b)
__device__ inline unsigned pkbf(float a, float b) {
    union { __hip_bfloat162 h2; unsigned u; } c;
    c.h2 = __float22bfloat162_rn(make_float2(a, b));
    return c.u;
}

__device__ inline bf16x8 bneg(bf16x8 v) {
    union { bf16x8 b; unsigned u[4]; } x; x.b = v;
    x.u[0] ^= 0x80008000u; x.u[1] ^= 0x80008000u;
    x.u[2] ^= 0x80008000u; x.u[3] ^= 0x80008000u;
    return x.b;
}

// ---------------------------------------------------------------------------
// pt2[a][bq][s] = pt[a][s*8+bq]
// ---------------------------------------------------------------------------
__global__ __launch_bounds__(256) void permute_pt_kernel(
    const int* __restrict__ pt, int* __restrict__ pt2)
{
    const int t = blockIdx.x * 256 + threadIdx.x;   // 16384
    const int a = t >> 11, r = t & 2047;
    const int bq = r >> 8, s = r & 255;
    pt2[t] = pt[a * NS + s * 8 + bq];
}

// ---------------------------------------------------------------------------
// fft_x: x[b,i,s*8+a] -> A-fragments, plane-major:
// xf[(kb*8 + mt*4 + v)*NCS*512 + cs*512 + lane*8 + j], v in {rh,rl,ih,il}
// ---------------------------------------------------------------------------
__global__ __launch_bounds__(256, 4) void fft_x_kernel(
    const float* __restrict__ x, ushort_t* __restrict__ xf, int i0, int KB)
{
    __shared__ float t_re[16][152], t_im[16][152];
    __shared__ ushort_t stgx[NCS * 68];
    const int tid = threadIdx.x;
    const int bp = blockIdx.x;   // 0..31
    const int il = blockIdx.y;   // 0..CI-1

    const int g = tid >> 4, l = tid & 15;
    const int bloc = g & 1, a = g >> 1;
    const int b = bp * 2 + bloc;
    const int i = i0 + il;

    // pass 1: row sy=l, real-input FFT-16 over sx, keep kx 0..8
    const float* xr_g = x + ((size_t)b * IFT + i) * NS;
    float xr[16], xi[16];
#pragma unroll
    for (int sx = 0; sx < 16; ++sx) { xr[sx] = xr_g[(l * 16 + sx) * 8 + a]; xi[sx] = 0.f; }
    fft16<false>(xr, xi);
#pragma unroll
    for (int kx = 0; kx < 9; ++kx) {
        t_re[g][kx * 17 + l] = xr[DR4[kx]];
        t_im[g][kx * 17 + l] = xi[DR4[kx]];
    }
    __syncthreads();

    // pass 2: column kx=l (l<9), complex FFT-16 over sy
    if (l < 9) {
        float Tr[16], Ti[16];
#pragma unroll
        for (int n = 0; n < 16; ++n) { Tr[n] = t_re[g][l * 17 + n]; Ti[n] = t_im[g][l * 17 + n]; }
        fft16<false>(Tr, Ti);
#pragma unroll
        for (int ky = 0; ky < 16; ++ky) {
            const float sr = Tr[DR4[ky]], si = Ti[DR4[ky]];
            const int cs = ky * 9 + l;
            const unsigned w0 = pkbf(sr, si);                       // rh | ih<<16
            const float rhf = bf2f((ushort_t)(w0 & 0xffffu));
            const float ihf = bf2f((ushort_t)(w0 >> 16));
            const unsigned w1 = pkbf(sr - rhf, si - ihf);           // rl | il<<16
            *(uint2*)&stgx[cs * 68 + bloc * 32 + a * 4] = make_uint2(w0, w1);
        }
    }
    __syncthreads();

    // fragment assembly, plane-major write
    const int kb = il >> 1, mt = bp >> 4;
    const int lb = (il & 1) * 32 + (bp & 15) * 2;
    const size_t PS = (size_t)NCS * 512;
    for (int t = tid; t < NCS * 8; t += 256) {
        const int cs = t >> 3, v4 = (t >> 1) & 3, h = t & 1;
        // ushort slot within 4-group: v {rh,rl,ih,il} -> {0,2,1,3}
        const int us = ((v4 & 1) << 1) | (v4 >> 1);
        union { ushort_t s[8]; uint4 u; } tmp;
        const int base = cs * 68 + h * 32 + us;
#pragma unroll
        for (int j = 0; j < 8; ++j) tmp.s[j] = stgx[base + j * 4];
        const size_t off = (size_t)(kb * 8 + mt * 4 + v4) * PS + (size_t)cs * 512 + (size_t)(lb + h) * 8;
        *(uint4*)(xf + off) = tmp.u;
    }
}

// ---------------------------------------------------------------------------
// fft_k: gather kernel[f,i,pt[a][s*8+bq]] -> B-fragments, plane-major:
// kf[(kb*32 + nt*2 + v)*NCS*512 + cs*512 + lane*8 + j], v in {re, im}
// Complex-pair pass-1 (z = f0row + i*f1row, one packed FFT per f-pair) +
// Hermitian split (F0 -> t2, F1 parked in regs). Round-7 barrier structure,
// packed thread mapping in pass-2, round-7 kf layout. krow2 aliases t2 low.
// ---------------------------------------------------------------------------
__global__ __launch_bounds__(256, 4) void fft_k_kernel(
    const float* __restrict__ kern, const int* __restrict__ pt2,
    ushort_t* __restrict__ kf, int i0, int KB)
{
    __shared__ __align__(16) f32x2 t2[16 * 153];       // 19584 B; first 2048 double as krow2
    __shared__ __align__(16) unsigned stgk[NCS * 18];  // 10368 B
    f32x2* krow2 = &t2[0];

    const int tid = threadIdx.x;
    const int fg  = blockIdx.x & 15;   // slow-varying f-group for XCD locality
    const int bqp = blockIdx.x >> 4;
    const int il  = blockIdx.y;
    const int i   = i0 + il;

    const int g = tid >> 4, l = tid & 15;
    const int bql = g & 1, a = g >> 1;
    const int bq  = bqp * 2 + bql;

    // gather indices (constant across rounds)
    int idx[16];
    const int4* pp = (const int4*)(pt2 + ((a * 8 + bq) * 256 + l * 16));
#pragma unroll
    for (int q = 0; q < 4; ++q) {
        const int4 t4 = pp[q];
        idx[q * 4] = t4.x; idx[q * 4 + 1] = t4.y; idx[q * 4 + 2] = t4.z; idx[q * 4 + 3] = t4.w;
    }

    const int kb = il >> 1;
    const int nt = fg;
    // packed pass-2 mapping: column job tid<144 -> transform pg, column pl
    const int pg = (tid * 57) >> 9;       // tid/9 for tid<144
    const int pl = tid - pg * 9;
    const int slot = (pg & 1) * 8 + (pg >> 1);
    const size_t PS = (size_t)NCS * 512;

    for (int p = 0; p < 2; ++p) {
        const int f0 = fg * 4 + p * 2;
        // stage interleaved rows (f0, f0+1); t2/krow2 free (trailing sync of prev iter)
        {
            const float4* s0 = (const float4*)(kern + ((size_t)f0 * IFT + i) * NS);
            const float4* s1 = (const float4*)(kern + ((size_t)(f0 + 1) * IFT + i) * NS);
            for (int u = tid; u < 512; u += 256) {
                const float4 va = s0[u], vb = s1[u];
                float4* dst = (float4*)(krow2 + (size_t)u * 4);
                dst[0] = make_float4(va.x, vb.x, va.y, vb.y);
                dst[1] = make_float4(va.z, vb.z, va.w, vb.w);
            }
        }
        __syncthreads();
        // complex-pair gather: z = f0row + i*f1row (row sy = l)
        f32x2 z[16];
#pragma unroll
        for (int sx = 0; sx < 16; ++sx) z[sx] = krow2[idx[sx]];
        __syncthreads();   // krow2 dead; region becomes t2 rows

        // pass 1: one packed complex FFT for both f's; Hermitian split
        fft16c<false>(z);
        f32x2 F1[9];
#pragma unroll
        for (int kx = 0; kx < 9; ++kx) {
            const f32x2 Zk = z[DR4[kx]];
            const f32x2 Zm = z[DR4[(16 - kx) & 15]];
            f32x2 F0;
            F0.x = (Zk.x + Zm.x) * 0.5f;
            F0.y = (Zk.y - Zm.y) * 0.5f;
            F1[kx].x = (Zk.y + Zm.y) * 0.5f;
            F1[kx].y = (Zm.x - Zk.x) * 0.5f;
            t2[g * 153 + kx * 17 + l] = F0;
        }

        for (int sub = 0; sub < 2; ++sub) {
            if (sub == 1) {
                // previous trailing sync guarantees sub=0 t2 reads are done
#pragma unroll
                for (int kx = 0; kx < 9; ++kx) t2[g * 153 + kx * 17 + l] = F1[kx];
            }
            __syncthreads();   // t2 visible block-wide

            // pass 2 packed: complex FFT-16 over sy, 144 active threads
            if (tid < 144) {
                f32x2 c[16];
#pragma unroll
                for (int n = 0; n < 16; ++n) c[n] = t2[pg * 153 + pl * 17 + n];
                fft16c<false>(c);
#pragma unroll
                for (int ky = 0; ky < 16; ++ky) {
                    const int cs = ky * 9 + pl;
                    const f32x2 v = c[DR4[ky]];
                    stgk[cs * 18 + slot] = pkbf(v.x, v.y);
                }
            }
            __syncthreads();

            // fragment assembly, plane-major write (round-7 layout)
            const int f = f0 + sub;
            const int lbase = (il & 1) * 32 + (f & 3) * 8 + bqp * 2;
            for (int t = tid; t < NCS * 2; t += 256) {
                const int cs = t >> 1, h = t & 1;
                const int base = cs * 18 + h * 8;
                unsigned w[8];
                *(uint2*)&w[0] = *(const uint2*)&stgk[base];
                *(uint2*)&w[2] = *(const uint2*)&stgk[base + 2];
                *(uint2*)&w[4] = *(const uint2*)&stgk[base + 4];
                *(uint2*)&w[6] = *(const uint2*)&stgk[base + 6];
                union { ushort_t s[8]; uint4 u; } lo, hi;
#pragma unroll
                for (int j = 0; j < 8; ++j) { lo.s[j] = (ushort_t)(w[j] & 0xffffu); hi.s[j] = (ushort_t)(w[j] >> 16); }
                const size_t off = (size_t)(kb * 32 + nt * 2) * PS + (size_t)cs * 512 + (size_t)(lbase + h) * 8;
                *(uint4*)(kf + off) = lo.u;
                *(uint4*)(kf + off + PS) = hi.u;
            }
            __syncthreads();
        }
    }
}

// ---------------------------------------------------------------------------
// MFMA complex GEMM, A split-bf16 (hi/lo), B plain bf16, no LDS.
// Plane-major operands; grid (NCS, 4) so same-cs blocks share an XCD (A in L2).
// ---------------------------------------------------------------------------
#define MFMA(acc, A, Bv) acc = __builtin_amdgcn_mfma_f32_32x32x16_bf16(A, Bv, acc, 0, 0, 0)
#define LDB(p) (*(const bf16x8*)(p))

__global__ __launch_bounds__(256) void gemm_kernel(
    const ushort_t* __restrict__ xf, const ushort_t* __restrict__ kf,
    float* __restrict__ yre, float* __restrict__ yim, int KB, int acc)
{
    const int cs = blockIdx.x, nb = blockIdx.y;
    const int w = threadIdx.x >> 6, lane = threadIdx.x & 63;
    const int nt = nb * 4 + w;
    const size_t PS = (size_t)NCS * 512;

    f32x16 cre0, cim0, cre1, cim1;
#pragma unroll
    for (int q = 0; q < 16; ++q) { cre0[q] = 0.f; cim0[q] = 0.f; cre1[q] = 0.f; cim1[q] = 0.f; }

    const ushort_t* ab = xf + (size_t)cs * 512 + (size_t)lane * 8;
    const ushort_t* bb = kf + (size_t)cs * 512 + (size_t)(nt * 2) * PS + (size_t)lane * 8;

    const ushort_t* ap = ab;                 // planes kb*8 + {0..7}
    const ushort_t* bp = bb;                 // planes kb*32 + nt*2 + {0,1}
    bf16x8 Brh = LDB(bp), Bih = LDB(bp + PS);
    bf16x8 Arh0 = LDB(ap), Arl0 = LDB(ap + PS), Aih0 = LDB(ap + 2 * PS), Ail0 = LDB(ap + 3 * PS);
    bf16x8 Arh1 = LDB(ap + 4 * PS), Arl1 = LDB(ap + 5 * PS), Aih1 = LDB(ap + 6 * PS), Ail1 = LDB(ap + 7 * PS);

    for (int kb = 0; kb < KB; ++kb) {
        const int kn = (kb + 1 < KB) ? kb + 1 : kb;
        const ushort_t* an = ab + (size_t)kn * 8 * PS;
        const ushort_t* bn = bb + (size_t)kn * 32 * PS;
        const bf16x8 nBrh = LDB(bn), nBih = LDB(bn + PS);
        const bf16x8 nArh0 = LDB(an), nArl0 = LDB(an + PS), nAih0 = LDB(an + 2 * PS), nAil0 = LDB(an + 3 * PS);
        const bf16x8 nArh1 = LDB(an + 4 * PS), nArl1 = LDB(an + 5 * PS), nAih1 = LDB(an + 6 * PS), nAil1 = LDB(an + 7 * PS);

        const bf16x8 NAih0 = bneg(Aih0), NAil0 = bneg(Ail0);
        const bf16x8 NAih1 = bneg(Aih1), NAil1 = bneg(Ail1);

        MFMA(cre0, Arh0, Brh); MFMA(cre0, Arl0, Brh);
        MFMA(cre0, NAih0, Bih); MFMA(cre0, NAil0, Bih);
        MFMA(cim0, Arh0, Bih); MFMA(cim0, Arl0, Bih);
        MFMA(cim0, Aih0, Brh); MFMA(cim0, Ail0, Brh);
        MFMA(cre1, Arh1, Brh); MFMA(cre1, Arl1, Brh);
        MFMA(cre1, NAih1, Bih); MFMA(cre1, NAil1, Bih);
        MFMA(cim1, Arh1, Bih); MFMA(cim1, Arl1, Bih);
        MFMA(cim1, Aih1, Brh); MFMA(cim1, Ail1, Brh);

        Brh = nBrh; Bih = nBih;
        Arh0 = nArh0; Arl0 = nArl0; Aih0 = nAih0; Ail0 = nAil0;
        Arh1 = nArh1; Arl1 = nArl1; Aih1 = nAih1; Ail1 = nAil1;
    }

    // C/D layout: col=lane&31, row=(reg&3)+8*(reg>>2)+4*(lane>>5)
    const int col = lane & 31, rhi = (lane >> 5) * 4;
    const int n = nb * 128 + w * 32 + col;
#pragma unroll
    for (int mt = 0; mt < 2; ++mt) {
        const f32x16 cr = mt ? cre1 : cre0;
        const f32x16 ci = mt ? cim1 : cim0;
#pragma unroll
        for (int reg = 0; reg < 16; ++reg) {
            const int row = (reg & 3) + 8 * (reg >> 2) + rhi;
            const size_t off = ((size_t)cs * B + mt * 32 + row) * 512 + n;
            float vr = cr[reg], vi = ci[reg];
            if (acc) { vr += yre[off]; vi += yim[off]; }
            yre[off] = vr; yim[off] = vi;
        }
    }
}

// ---------------------------------------------------------------------------
// ifft: mirror half-spectrum (cs = ky*9+kx), 2D inverse FFT, +bias.
// ---------------------------------------------------------------------------
__global__ __launch_bounds__(256, 4) void ifft_y_kernel(
    const float* __restrict__ yre, const float* __restrict__ yim,
    const float* __restrict__ bias, float* __restrict__ out)
{
    __shared__ float yr_s[NCS][17], yi_s[NCS][17];
    __shared__ float t_re[16][271], t_im[16][271];
    __shared__ float ost[2][256][9];
    const int tid = threadIdx.x;
    const int ng = blockIdx.x;   // 0..31
    const int b = blockIdx.y;
    const int n0 = ng * 16;
    for (int t = tid; t < NCS * 16; t += 256) {
        const int cs = t >> 4, nl = t & 15;
        const size_t off = ((size_t)cs * B + b) * 512 + n0 + nl;
        yr_s[cs][nl] = yre[off];
        yi_s[cs][nl] = yim[off];
    }
    __syncthreads();

    const int g = tid >> 4, l = tid & 15;

    // pass 1: row ky=l, Hermitian mirror, inverse FFT-16 over kx
    float Yr[16], Yi[16];
#pragma unroll
    for (int kx = 0; kx < 16; ++kx) {
        if (kx <= 8) {
            const int cs = l * 9 + kx;
            Yr[kx] = yr_s[cs][g]; Yi[kx] = yi_s[cs][g];
        } else {
            const int cs = ((16 - l) & 15) * 9 + (16 - kx);
            Yr[kx] = yr_s[cs][g]; Yi[kx] = -yi_s[cs][g];
        }
    }
    fft16<true>(Yr, Yi);
#pragma unroll
    for (int sx = 0; sx < 16; ++sx) {
        t_re[g][sx * 17 + l] = Yr[DR4[sx]];
        t_im[g][sx * 17 + l] = Yi[DR4[sx]];
    }
    __syncthreads();

    // pass 2: column sx=l, inverse FFT-16 over ky, real part only
    float Tr[16], Ti[16];
#pragma unroll
    for (int n = 0; n < 16; ++n) { Tr[n] = t_re[g][l * 17 + n]; Ti[n] = t_im[g][l * 17 + n]; }
    fft16<true>(Tr, Ti);
    const int fl = g >> 3, pq = g & 7;
#pragma unroll
    for (int sy = 0; sy < 16; ++sy)
        ost[fl][sy * 16 + l][pq] = Tr[DR4[sy]] * (1.f / 256.f);
    __syncthreads();

    const int f0 = ng * 2;
    for (int t = tid; t < 4096; t += 256) {
        const int flv = t >> 11, e = t & 2047;
        out[((size_t)b * F + f0 + flv) * NS + e] = ost[flv][e >> 3][e & 7] + bias[f0 + flv];
    }
}

// ---------------------------------------------------------------------------
extern "C" void kernel_launch(void* const* d_in, const int* in_sizes, int n_in,
                              void* d_out, int out_size, void* d_ws, size_t ws_size,
                              hipStream_t stream)
{
    const float* x = (const float*)d_in[0];
    const float* kern = (const float*)d_in[1];
    const float* bias = (const float*)d_in[2];
    const int* pt = (const int*)d_in[3];
    float* out = (float*)d_out;

    // largest in-feature chunk CI that fits workspace
    int CI = 2;
    const int cands[6] = {64, 32, 16, 8, 4, 2};
    for (int t = 0; t < 6; ++t) {
        const int KBc = cands[t] / 2;
        const size_t need = 65536                          // pt2
                          + (size_t)NCS * KBc * 8192       // xf (4 planes bf16)
                          + (size_t)NCS * KBc * 32768      // kf (2 planes bf16)
                          + 2 * (size_t)NCS * B * 512 * 4; // yf re/im fp32
        if (need <= ws_size) { CI = cands[t]; break; }
    }
    const int KB = CI / 2;

    char* p = (char*)d_ws;
    int* pt2 = (int*)p;          p += 65536;
    ushort_t* xf = (ushort_t*)p; p += (size_t)NCS * KB * 8192;
    ushort_t* kf = (ushort_t*)p; p += (size_t)NCS * KB * 32768;
    float* yre = (float*)p;      p += (size_t)NCS * B * 512 * 4;
    float* yim = (float*)p;

    permute_pt_kernel<<<64, 256, 0, stream>>>(pt, pt2);

    const int nch = IFT / CI;
    for (int ch = 0; ch < nch; ++ch) {
        const int i0 = ch * CI;
        fft_x_kernel<<<dim3(32, CI), 256, 0, stream>>>(x, xf, i0, KB);
        fft_k_kernel<<<dim3(64, CI), 256, 0, stream>>>(kern, pt2, kf, i0, KB);
        gemm_kernel<<<dim3(NCS, 4), 256, 0, stream>>>(xf, kf, yre, yim, KB, ch > 0);
    }
    ifft_y_kernel<<<dim3(32, B), 256, 0, stream>>>(yre, yim, bias, out);
}